// Round 1
// baseline (116.341 us; speedup 1.0000x reference)
//
#include <hip/hip_runtime.h>
#include <hip/hip_fp16.h>

// grid : (B=4, gh=16, gw=16, gd=8, nc=12)  fp32
// guide: (B=4, H=1024, W=1024)             fp32
// inp  : (B=4, H=1024, W=1024, 3)          fp32
// out  : (B=4, H=1024, W=1024, 3)          fp32
//
// Block = 64x32 pixel tile. Stage 1: x-interp grid, packed to fp16 in LDS:
//   region A: [yc:2][z:8][x:64] -> 4x half2 (channels 0..7)          16 KB
//   region B: [z:8][x:64]      -> {ycA:(c8,c9),(c10,c11), ycB:same}   8 KB
// Stage 2: ROLLING distance-2 prefetch of guide+inp (3 statically rotated
// slots, ~12 VGPR instead of 32 for the old 8-row monolithic prefetch),
// then per row: 6 conflict-free ds_read_b128, y/z lerp in packed fp16,
// affine apply in packed fp16, f32 store.
//
// launch_bounds(256,5): VGPR cap 102 -> 5 waves/SIMD; LDS 24KB*5 = 120KB
// -> 20 waves/CU (was 16 at (256,4)) for latency hiding.

struct __align__(16) H2x4 { __half2 x, y, z, w; };
struct __align__(8)  H2x2 { __half2 a, b; };

__global__ __launch_bounds__(256, 5) void BilateralSliceApply_kernel(
    const float* __restrict__ grid,
    const float* __restrict__ guide,
    const float* __restrict__ inp,
    float* __restrict__ out)
{
    __shared__ H2x4 lA[1024];  // (yc*8+z)*64 + x   16 KB
    __shared__ H2x4 lB[512];   // z*64 + x           8 KB

    const int tx = blockIdx.x;    // 0..15
    const int ty = blockIdx.y;    // 0..31
    const int b  = blockIdx.z;    // 0..3
    const int t  = threadIdx.x;   // 0..255
    const int xl = t & 63;

    const int x0 = tx << 6;
    const int y0 = ty << 5;

    const int fy  = (ty == 0) ? -1 : ((ty - 1) >> 1);
    const int ycA = fy < 0 ? 0 : fy;
    const int ycB = (fy + 1 > 15) ? 15 : fy + 1;

    // ---------------- stage 1 setup: x-interp -> fp16 LDS ----------------
    const int fx  = (xl < 32) ? (tx - 1) : tx;
    const int ix0 = fx < 0 ? 0 : fx;
    const int ix1 = (fx + 1 > 15) ? 15 : fx + 1;
    const float wx1 = ((float)(x0 + xl) + 0.5f) * 0.015625f - 0.5f - (float)fx;

    const int bbase = b << 4;
    const int g0grp = t >> 6;  // 0..3

    const int r0 = t >> 6;  // 0..3 ; rows r0+4k
    const int pp0 = (((b << 10) + y0 + r0) << 10) + x0 + xl;

    // ---- rolling prefetch, distance 2: prologue rows 0 and 1 ----
    float  gzb[3];
    float3 inb[3];
    gzb[0] = guide[pp0];
    inb[0] = *(const float3*)(inp + (size_t)pp0 * 3);
    {
        const int pp1 = pp0 + (1 << 12);
        gzb[1] = guide[pp1];
        inb[1] = *(const float3*)(inp + (size_t)pp1 * 3);
    }

#pragma unroll
    for (int q = 0; q < 4; ++q) {
        const int L  = g0grp + (q << 2);   // 0..15
        const int yc = L >> 3;
        const int z  = L & 7;
        const int ycell = yc ? ycB : ycA;
        const int cb = (bbase + ycell) << 4;
        const float* p0 = grid + (size_t)(((cb + ix0) << 3) + z) * 12;
        const float* p1 = grid + (size_t)(((cb + ix1) << 3) + z) * 12;
        const float4 a0 = *(const float4*)(p0 + 0);
        const float4 a1 = *(const float4*)(p0 + 4);
        const float4 a2 = *(const float4*)(p0 + 8);
        const float4 b0 = *(const float4*)(p1 + 0);
        const float4 b1 = *(const float4*)(p1 + 4);
        const float4 b2 = *(const float4*)(p1 + 8);
        const float v0  = fmaf(wx1, b0.x - a0.x, a0.x);
        const float v1  = fmaf(wx1, b0.y - a0.y, a0.y);
        const float v2  = fmaf(wx1, b0.z - a0.z, a0.z);
        const float v3  = fmaf(wx1, b0.w - a0.w, a0.w);
        const float v4  = fmaf(wx1, b1.x - a1.x, a1.x);
        const float v5  = fmaf(wx1, b1.y - a1.y, a1.y);
        const float v6  = fmaf(wx1, b1.z - a1.z, a1.z);
        const float v7  = fmaf(wx1, b1.w - a1.w, a1.w);
        const float v8  = fmaf(wx1, b2.x - a2.x, a2.x);
        const float v9  = fmaf(wx1, b2.y - a2.y, a2.y);
        const float v10 = fmaf(wx1, b2.z - a2.z, a2.z);
        const float v11 = fmaf(wx1, b2.w - a2.w, a2.w);

        H2x4 rowA;
        rowA.x = __floats2half2_rn(v0, v1);
        rowA.y = __floats2half2_rn(v2, v3);
        rowA.z = __floats2half2_rn(v4, v5);
        rowA.w = __floats2half2_rn(v6, v7);
        lA[(L << 6) + xl] = rowA;

        H2x2 rowB;
        rowB.a = __floats2half2_rn(v8, v9);
        rowB.b = __floats2half2_rn(v10, v11);
        ((H2x2*)lB)[(((z << 6) + xl) << 1) + yc] = rowB;
    }
    __syncthreads();

    // ---------------- stage 2: y/z lerp + affine (packed fp16) ----------------
    // wy1 for row r0+4k: base + k * (4/64)
    const float wyb = ((float)(y0 + r0) + 0.5f) * 0.015625f - 0.5f - (float)fy;

#pragma unroll
    for (int k = 0; k < 8; ++k) {
        // issue prefetch for row k+2 (statically rotated slot)
        if (k + 2 < 8) {
            const int ppn = pp0 + ((k + 2) << 12);   // +4 rows = +4096 px
            gzb[(k + 2) % 3] = guide[ppn];
            inb[(k + 2) % 3] = *(const float3*)(inp + (size_t)ppn * 3);
        }

        const float wy1 = wyb + 0.0625f * (float)k;
        const float wy0 = 1.0f - wy1;
        const int pp = pp0 + (k << 12);

        const float gz  = gzb[k % 3] * 8.0f;
        const float fz  = floorf(gz - 0.5f);
        const float wz1 = gz - 0.5f - fz;
        const float wz0 = 1.0f - wz1;
        const int ifz = (int)fz;
        const int iz0 = ifz < 0 ? 0 : (ifz > 7 ? 7 : ifz);
        const int nz  = ifz + 1;
        const int iz1 = nz < 0 ? 0 : (nz > 7 ? 7 : nz);

        const __half2 hA0 = __float2half2_rn(wy0 * wz0);
        const __half2 hA1 = __float2half2_rn(wy0 * wz1);
        const __half2 hB0 = __float2half2_rn(wy1 * wz0);
        const __half2 hB1 = __float2half2_rn(wy1 * wz1);

        const H2x4 vA00 = lA[(iz0 << 6) + xl];         // ycA, z0
        const H2x4 vA01 = lA[(iz1 << 6) + xl];         // ycA, z1
        const H2x4 vA10 = lA[((8 + iz0) << 6) + xl];   // ycB, z0
        const H2x4 vA11 = lA[((8 + iz1) << 6) + xl];   // ycB, z1
        const H2x4 vB0  = lB[(iz0 << 6) + xl];         // {ycA c8-11, ycB c8-11}, z0
        const H2x4 vB1  = lB[(iz1 << 6) + xl];

        __half2 q0 = __hmul2(hA0, vA00.x);             // (c0,c1)
        __half2 q1 = __hmul2(hA0, vA00.y);             // (c2,c3)
        __half2 q2 = __hmul2(hA0, vA00.z);             // (c4,c5)
        __half2 q3 = __hmul2(hA0, vA00.w);             // (c6,c7)
        q0 = __hfma2(hA1, vA01.x, q0);
        q1 = __hfma2(hA1, vA01.y, q1);
        q2 = __hfma2(hA1, vA01.z, q2);
        q3 = __hfma2(hA1, vA01.w, q3);
        q0 = __hfma2(hB0, vA10.x, q0);
        q1 = __hfma2(hB0, vA10.y, q1);
        q2 = __hfma2(hB0, vA10.z, q2);
        q3 = __hfma2(hB0, vA10.w, q3);
        q0 = __hfma2(hB1, vA11.x, q0);
        q1 = __hfma2(hB1, vA11.y, q1);
        q2 = __hfma2(hB1, vA11.z, q2);
        q3 = __hfma2(hB1, vA11.w, q3);

        __half2 q4 = __hmul2(hA0, vB0.x);              // (c8,c9)
        __half2 q5 = __hmul2(hA0, vB0.y);              // (c10,c11)
        q4 = __hfma2(hA1, vB1.x, q4);
        q5 = __hfma2(hA1, vB1.y, q5);
        q4 = __hfma2(hB0, vB0.z, q4);
        q5 = __hfma2(hB0, vB0.w, q5);
        q4 = __hfma2(hB1, vB1.z, q4);
        q5 = __hfma2(hB1, vB1.w, q5);

        // affine in packed fp16: out_o = dot((c_{4o},c_{4o+1}),(in0,in1))
        //                              + dot((c_{4o+2},c_{4o+3}),(in2,1))
        const float3 in = inb[k % 3];
        const __half2 i01 = __floats2half2_rn(in.x, in.y);
        const __half2 i21 = __floats2half2_rn(in.z, 1.0f);

        __half2 r0h = __hmul2(q0, i01); r0h = __hfma2(q1, i21, r0h);
        __half2 r1h = __hmul2(q2, i01); r1h = __hfma2(q3, i21, r1h);
        __half2 r2h = __hmul2(q4, i01); r2h = __hfma2(q5, i21, r2h);

        float3 o;
        o.x = __low2float(r0h) + __high2float(r0h);
        o.y = __low2float(r1h) + __high2float(r1h);
        o.z = __low2float(r2h) + __high2float(r2h);
        *(float3*)(out + (size_t)pp * 3) = o;
    }
}

extern "C" void kernel_launch(void* const* d_in, const int* in_sizes, int n_in,
                              void* d_out, int out_size, void* d_ws, size_t ws_size,
                              hipStream_t stream) {
    const float* grid  = (const float*)d_in[0];
    const float* guide = (const float*)d_in[1];
    const float* inp   = (const float*)d_in[2];
    float* out = (float*)d_out;

    dim3 gridDim(16, 32, 4);
    BilateralSliceApply_kernel<<<gridDim, 256, 0, stream>>>(grid, guide, inp, out);
}